// Round 15
// baseline (38.184 us; speedup 1.0000x reference)
//
#include <hip/hip_runtime.h>
#include <cmath>

#define BN 8192
#define DIM 128
#define MARGIN_F 0.3f
#define NSPLIT 8            // column splits (1024 cols each)
#define CPS 1024
#define NT 8                // 128-col B tiles per panel
#define NPART (NSPLIT * 2)  // per-row partials: split x wc
#define FBLK 32
#define NLAB 128
#define NG 64               // 128-row groups for ranking
#define IMAX 0x7FFFFFFF
#define IMIN 0x80000000

typedef __attribute__((ext_vector_type(4))) int i32x4;

__device__ __forceinline__ int imin3(int a, int b, int c) { return min(a, min(b, c)); }
__device__ __forceinline__ int imax3(int a, int b, int c) { return max(a, max(b, c)); }

// ---------------- K0a: per-group histogram + local rank (LDS atomics only) ----------------
__global__ __launch_bounds__(256) void hist_rank_k(
    const int* __restrict__ lab, int* __restrict__ ghist, int* __restrict__ lrank)
{
  __shared__ int lh[NLAB];
  const int t = threadIdx.x, b = blockIdx.x;
  if (t < NLAB) lh[t] = 0;
  __syncthreads();
  if (t < 128) {
    int i = b * 128 + t;
    int l = lab[i] & (NLAB - 1);
    lrank[i] = atomicAdd(&lh[l], 1);   // order within label irrelevant (min/max over sets)
  }
  __syncthreads();
  if (t < NLAB) ghist[t * NG + b] = lh[t];
}

// ---------------- K0b: per-label group-offsets + bin scan; zero gacc ----------------
__global__ __launch_bounds__(128) void scan_k(
    const int* __restrict__ ghist, int* __restrict__ offArr,
    int* __restrict__ binStart, float* __restrict__ gacc)
{
  __shared__ int tot[NLAB];
  const int l = threadIdx.x;     // 128 threads, one per label
  if (l < 3) gacc[l] = 0.f;
  int run = 0;
  #pragma unroll 8
  for (int b = 0; b < NG; ++b) {
    offArr[l * NG + b] = run;
    run += ghist[l * NG + b];
  }
  tot[l] = run;                  // total count of label l
  __syncthreads();
  #pragma unroll
  for (int off = 1; off < NLAB; off <<= 1) {   // Hillis-Steele inclusive scan
    int v = (l >= off) ? tot[l - off] : 0;
    __syncthreads();
    tot[l] += v;
    __syncthreads();
  }
  binStart[l] = tot[l] - run;    // exclusive prefix
}

// ---------------- K1: norms + i8 quantize + label-sorted scatter (no atomics) ----------------
// dst = binStart[l] + offArr[l][group] + lrank[row]: a bijection onto [0,BN) grouping
// equal labels contiguously. Scatter write pattern identical in shape to unsorted.
__global__ __launch_bounds__(256) void norm_cvt_k(
    const float* __restrict__ emb, const int* __restrict__ lab,
    const int* __restrict__ binStart, const int* __restrict__ offArr,
    const int* __restrict__ lrank,
    float* __restrict__ sqvS, unsigned short* __restrict__ EnQ16,
    int* __restrict__ labS)
{
  int gt = blockIdx.x * blockDim.x + threadIdx.x;
  int w = gt >> 6;  // one wave per row
  int lane = threadIdx.x & 63;
  if (w >= BN) return;

  int lb = 0, dst = 0;
  if (lane == 0) {
    lb  = lab[w] & (NLAB - 1);
    dst = binStart[lb] + offArr[lb * NG + (w >> 7)] + lrank[w];
  }
  dst = __shfl(dst, 0);
  lb  = __shfl(lb, 0);

  float2 v = *reinterpret_cast<const float2*>(&emb[w * DIM + lane * 2]);
  float s = v.x * v.x + v.y * v.y;
  #pragma unroll
  for (int off = 32; off > 0; off >>= 1) s += __shfl_xor(s, off);
  float iv = 1.0f / fmaxf(sqrtf(s), 1e-12f);
  if (lane == 0) { sqvS[dst] = s * iv * iv; labS[dst] = lb; }
  int q0 = (int)rintf(127.0f * v.x * iv);
  int q1 = (int)rintf(127.0f * v.y * iv);
  unsigned short us = (unsigned short)((q0 & 255) | ((q1 & 255) << 8));
  int g = lane >> 3;                                  // k = 2*lane -> chunk g = lane/8
  EnQ16[(g * BN + dst) * 8 + (lane & 7)] = us;
}

// ---------------- K2: barrier-free i8-MFMA gram + sorted fast-path mining ----------------
// r8 structure (direct-L2 B reads, half-deep pipeline) + sorted labels: wave-uniform
// range test classifies each 64x64 tile; disjoint (~97%) -> mining is one v_max3 per
// (mi,r) (no label loads/selects); band tiles take the exact compare path (proven r9).
__global__ __launch_bounds__(256, 2) void gram_mine_mfma_k(
    const char* __restrict__ EnQ, const int* __restrict__ labS,
    int* __restrict__ ap_part, int* __restrict__ an_part)
{
  const int tid = threadIdx.x;
  const int w = tid >> 6, l = tid & 63;
  const int wr = w >> 1, wc = w & 1;
  const int lrow = l & 15, lkg = l >> 4;

  const int rowBase = blockIdx.x * 128 + wr * 64;   // this wave's 64 rows
  const int panel   = blockIdx.y * CPS;

  const int rLo = labS[rowBase], rHi = labS[rowBase + 63];   // sorted -> exact range

  // A fragments: 4 row-tiles x 2 K-steps (K=64 each), 16B per frag, coalesced
  i32x4 a[4][2];
  #pragma unroll
  for (int mi = 0; mi < 4; ++mi)
    #pragma unroll
    for (int kk = 0; kk < 2; ++kk)
      a[mi][kk] = *reinterpret_cast<const i32x4*>(
          EnQ + (((size_t)((kk << 2) + lkg) * BN + rowBase + mi * 16 + lrow) << 4));

  // row labels for the 16 rows this lane owns (sorted domain)
  int rlv[4][4];
  #pragma unroll
  for (int mi = 0; mi < 4; ++mi) {
    int rb = rowBase + mi * 16 + lkg * 4;
    #pragma unroll
    for (int r = 0; r < 4; ++r) rlv[mi][r] = labS[rb + r];
  }

  int ap[4][4], an[4][4];
  #pragma unroll
  for (int mi = 0; mi < 4; ++mi)
    #pragma unroll
    for (int r = 0; r < 4; ++r) { ap[mi][r] = IMAX; an[mi][r] = IMIN; }

  const i32x4 zf = {0, 0, 0, 0};   // shared zero C-operand

  // B pointers: two bases (kk=0,1), advanced 2048 B per 128-col tile
  const int colLane = wc * 64 + lrow;
  const char* bp0 = EnQ + (((size_t)lkg * BN + panel + colLane) << 4);
  const char* bp1 = bp0 + ((size_t)BN << 6);   // += 4*BN*16

  auto loadHalf = [&](i32x4 (&b)[2][2], const char* p0, const char* p1, int n0) {
    #pragma unroll
    for (int n = 0; n < 2; ++n) {
      b[0][n] = *reinterpret_cast<const i32x4*>(p0 + (n0 + n) * 256);
      b[1][n] = *reinterpret_cast<const i32x4*>(p1 + (n0 + n) * 256);
    }
  };
  auto mfmaHalf = [&](i32x4 (&A)[4][2], const i32x4 (&b)[2][2]) {
    #pragma unroll
    for (int mi = 0; mi < 4; ++mi)
      #pragma unroll
      for (int n = 0; n < 2; ++n)
        A[mi][n] = __builtin_amdgcn_mfma_i32_16x16x64_i8(a[mi][0], b[0][n], zf, 0, 0, 0);
    #pragma unroll
    for (int mi = 0; mi < 4; ++mi)
      #pragma unroll
      for (int n = 0; n < 2; ++n)
        A[mi][n] = __builtin_amdgcn_mfma_i32_16x16x64_i8(a[mi][1], b[1][n], A[mi][n], 0, 0, 0);
  };

  auto mineFast = [&](const i32x4 (&A)[4][2]) {   // disjoint ranges: all negatives
    #pragma unroll
    for (int mi = 0; mi < 4; ++mi)
      #pragma unroll
      for (int r = 0; r < 4; ++r)
        an[mi][r] = imax3(an[mi][r], A[mi][0][r], A[mi][1][r]);
  };
  auto mineMixed = [&](const i32x4 (&A)[4][2], int l0, int l1, int c0, int c1, bool dg) {
    if (!dg) {
      #pragma unroll
      for (int mi = 0; mi < 4; ++mi)
        #pragma unroll
        for (int r = 0; r < 4; ++r) {
          int d0 = A[mi][0][r], d1 = A[mi][1][r];
          bool s0 = (rlv[mi][r] == l0), s1 = (rlv[mi][r] == l1);
          int p0 = s0 ? d0 : IMAX;
          int p1 = s1 ? d1 : IMAX;
          int q0 = s0 ? IMIN : d0;
          int q1 = s1 ? IMIN : d1;
          ap[mi][r] = imin3(ap[mi][r], p0, p1);
          an[mi][r] = imax3(an[mi][r], q0, q1);
        }
    } else {
      #pragma unroll
      for (int mi = 0; mi < 4; ++mi)
        #pragma unroll
        for (int r = 0; r < 4; ++r) {
          int rloc = mi * 16 + lkg * 4 + r;
          int d0 = A[mi][0][r], d1 = A[mi][1][r];
          bool s0 = (rlv[mi][r] == l0), s1 = (rlv[mi][r] == l1);
          bool e0 = (rloc == c0), e1 = (rloc == c1);
          int p0 = (s0 && !e0) ? d0 : IMAX;
          int p1 = (s1 && !e1) ? d1 : IMAX;
          int q0 = s0 ? IMIN : d0;
          int q1 = s1 ? IMIN : d1;
          ap[mi][r] = imin3(ap[mi][r], p0, p1);
          an[mi][r] = imax3(an[mi][r], q0, q1);
        }
    }
  };

  i32x4 accA[4][2], accB[4][2];
  i32x4 bA[2][2], bB[2][2];
  int lp0 = 0, lp1 = 0;
  bool diagP = false, mixedP = false;

  loadHalf(bA, bp0, bp1, 0);   // tile 0, half 0

  #pragma unroll 1
  for (int ct = 0; ct < NT; ++ct) {
    const int colBase = panel + ct * 128 + wc * 64;
    const int cLo = labS[colBase], cHi = labS[colBase + 63];
    const bool mixed = (cHi >= rLo) && (cLo <= rHi);
    const bool diag  = (rowBase == colBase);          // diag => mixed

    int l0 = 0, l1 = 0, l2 = 0, l3 = 0;
    if (mixed) {
      l0 = labS[colBase + lrow];       l1 = labS[colBase + 16 + lrow];
      l2 = labS[colBase + 32 + lrow];  l3 = labS[colBase + 48 + lrow];
    }

    loadHalf(bB, bp0, bp1, 2);           // this tile, half 1 (in flight)
    mfmaHalf(accA, bA);                  // half 0 MFMA (waits on bA)
    if (ct > 0) {                        // previous tile's half 1
      if (mixedP) mineMixed(accB, lp0, lp1, 32 + lrow, 48 + lrow, diagP);
      else        mineFast(accB);
    }

    bp0 += 2048; bp1 += 2048;
    if (ct + 1 < NT) loadHalf(bA, bp0, bp1, 0);   // next tile, half 0 (in flight)

    mfmaHalf(accB, bB);                  // half 1 MFMA
    if (mixed) mineMixed(accA, l0, l1, 0 + lrow, 16 + lrow, diag);
    else       mineFast(accA);

    lp0 = l2; lp1 = l3; diagP = diag; mixedP = mixed;
  }
  // drain: last tile's half 1
  if (mixedP) mineMixed(accB, lp0, lp1, 32 + lrow, 48 + lrow, diagP);
  else        mineFast(accB);

  // butterfly-reduce across the 16 lrow lanes sharing each C row, write partials
  const int part = blockIdx.y * 2 + wc;
  #pragma unroll
  for (int mi = 0; mi < 4; ++mi)
    #pragma unroll
    for (int r = 0; r < 4; ++r) {
      int p = ap[mi][r], n = an[mi][r];
      #pragma unroll
      for (int off = 1; off < 16; off <<= 1) {
        p = min(p, __shfl_xor(p, off));
        n = max(n, __shfl_xor(n, off));
      }
      if (lrow == 0) {
        int rg = rowBase + mi * 16 + lkg * 4 + r;
        ap_part[part * BN + rg] = p;
        an_part[part * BN + rg] = n;
      }
    }
}

// ---------------- K3: per-row combine + fused final scalar (r14, proven) ----------------
__global__ __launch_bounds__(256) void finalize_k(
    const int* __restrict__ ap_part, const int* __restrict__ an_part,
    const float* __restrict__ sqvS,
    float* __restrict__ gacc /* [0]=sum [1]=cnt [2]=ctr(int) */,
    float* __restrict__ out)
{
  int r = blockIdx.x * 256 + threadIdx.x;   // FBLK*256 == BN
  int apt = IMAX, ant = IMIN;
  #pragma unroll 8
  for (int s = 0; s < NPART; ++s) {
    apt = min(apt, ap_part[s * BN + r]);
    ant = max(ant, an_part[s * BN + r]);
  }
  float sum = 0.f, cnt = 0.f;
  if (apt != IMAX && ant != IMIN) {
    const float sc = 2.0f / (127.0f * 127.0f);
    float rs1 = sqvS[r] + 1.0f;
    float dap = sqrtf(fmaxf(fmaf(-sc, (float)apt, rs1), 0.f));
    float dan = sqrtf(fmaxf(fmaf(-sc, (float)ant, rs1), 0.f));
    sum = fmaxf(dap - dan + MARGIN_F, 0.f);
    cnt = 1.f;
  }
  #pragma unroll
  for (int off = 32; off > 0; off >>= 1) {
    sum += __shfl_xor(sum, off);
    cnt += __shfl_xor(cnt, off);
  }
  __shared__ float ssum[4], scnt[4];
  int wv = threadIdx.x >> 6;
  if ((threadIdx.x & 63) == 0) { ssum[wv] = sum; scnt[wv] = cnt; }
  __syncthreads();
  if (threadIdx.x == 0) {
    float bs = ssum[0] + ssum[1] + ssum[2] + ssum[3];
    float bc = scnt[0] + scnt[1] + scnt[2] + scnt[3];
    atomicAdd(&gacc[0], bs);
    atomicAdd(&gacc[1], bc);
    __threadfence();
    int old = atomicAdd((int*)&gacc[2], 1);
    if (old == FBLK - 1) {
      __threadfence();
      float s = atomicAdd(&gacc[0], 0.f);
      float c = atomicAdd(&gacc[1], 0.f);
      out[0] = (c > 0.f) ? (s / c) : 0.f;
      gacc[0] = 0.f; gacc[1] = 0.f; *(int*)&gacc[2] = 0;   // replay-friendly reset
    }
  }
}

extern "C" void kernel_launch(void* const* d_in, const int* in_sizes, int n_in,
                              void* d_out, int out_size, void* d_ws, size_t ws_size,
                              hipStream_t stream)
{
  const float* emb = (const float*)d_in[0];
  const int*   lab = (const int*)d_in[1];
  float* out = (float*)d_out;
  float* ws  = (float*)d_ws;

  float* sqvS     = ws;                             // BN floats
  int*   ap_part  = (int*)(sqvS + BN);              // NPART*BN ints
  int*   an_part  = ap_part + NPART * BN;           // NPART*BN ints
  int*   labS     = an_part + NPART * BN;           // BN
  int*   ghist    = labS + BN;                      // NLAB*NG
  int*   offArr   = ghist + NLAB * NG;              // NLAB*NG
  int*   lrank    = offArr + NLAB * NG;             // BN
  int*   binStart = lrank + BN;                     // NLAB
  float* gacc     = (float*)(binStart + NLAB);      // 16
  char*  EnQ      = (char*)(gacc + 16);             // BN*DIM i8, k-major (~1 MB)

  hist_rank_k<<<dim3(NG), 256, 0, stream>>>(lab, ghist, lrank);
  scan_k<<<dim3(1), 128, 0, stream>>>(ghist, offArr, binStart, gacc);
  norm_cvt_k<<<dim3(BN / 4), 256, 0, stream>>>(emb, lab, binStart, offArr, lrank,
                                               sqvS, (unsigned short*)EnQ, labS);
  gram_mine_mfma_k<<<dim3(BN / 128, NSPLIT), 256, 0, stream>>>(EnQ, labS, ap_part, an_part);
  finalize_k<<<dim3(FBLK), 256, 0, stream>>>(ap_part, an_part, sqvS, gacc, out);
}